// Round 12
// baseline (163.247 us; speedup 1.0000x reference)
//
#include <hip/hip_runtime.h>
#include <hip/hip_bf16.h>
#include <stdint.h>

#define N_SAMPLES 4096
#define M_ROWS 16
#define K_DIM 256
#define H_DIM 256
#define N_CATS 64
#define SPB 4                                        // samples per group (64 rows)
#define MAX_PADDED (N_SAMPLES + N_CATS * (SPB - 1))  // 4288
#define NGROUP (MAX_PADDED / SPB)                    // 1072
#define GPX (NGROUP / 8)                             // 134 groups per XCD
#define GEMM_GRID (NGROUP * 2)                       // 2144 units (group x h-half)
#define AROW 264                                     // small-tier fallback layout

typedef _Float16 half8 __attribute__((ext_vector_type(8)));
typedef _Float16 half4 __attribute__((ext_vector_type(4)));
typedef float floatx4 __attribute__((ext_vector_type(4)));

// async global->LDS DMA, 16B per lane (dest = uniform base + lane*16)
#define GLOAD_LDS(g, l)                                          \
  __builtin_amdgcn_global_load_lds(                              \
      (const __attribute__((address_space(1))) void*)(g),        \
      (__attribute__((address_space(3))) void*)(l), 16, 0, 0)

// ---- workspace layout ----
// full tier: Wt (8MB) | x16 (32MB, swizzled f16) | gcat | ord
#define WT_BYTES  ((size_t)N_CATS * K_DIM * H_DIM * 2)
#define X16_BYTES ((size_t)N_SAMPLES * M_ROWS * K_DIM * 2)
#define GCAT_OFF_F (WT_BYTES + X16_BYTES)
#define ORD_OFF_F  (GCAT_OFF_F + 4288)
#define WS_NEED_F  (ORD_OFF_F + (size_t)MAX_PADDED * 4)
// small tier (no x16): Wt | gcat | ord
#define GCAT_OFF_S WT_BYTES
#define ORD_OFF_S  (WT_BYTES + 4288)
#define WS_NEED_S  (ORD_OFF_S + (size_t)MAX_PADDED * 4)

// ---------------- balanced prep: 1025 blocks, deep load pipeline ----------------
// R11 post-mortem: prep was the slowest dispatch (48us) at VGPR=32 -- a
// latency-bound copy whose 16-deep x-load chain had ~2 loads in flight.
// Fix: launch_bounds(256,4) (128-VGPR budget) + explicitly batched issue
// order so >=12 float4 loads are in flight at all times:
//   issue 4 W-loads + 8 x-loads(A) -> W->LDS -> sync -> issue 8 x-loads(B)
//   -> cvt/store A -> Wt store -> cvt/store B.
// Addresses/swizzle identical to R11 (numerics unchanged).
__global__ __launch_bounds__(256, 4)
void prep_combined(const float* __restrict__ W, _Float16* __restrict__ Wt,
                   const int* __restrict__ cat, int* __restrict__ ord,
                   int* __restrict__ gcat,
                   const float* __restrict__ x, _Float16* __restrict__ x16) {
  const int tid = threadIdx.x;
  const int bid = blockIdx.x;
  if (bid < 1024) {
    __shared__ _Float16 t[64][72];
    const int c  = bid >> 4;
    const int kb = (bid >> 2) & 3;
    const int hb = bid & 3;
    const int r  = tid >> 2;
    const int cg = (tid & 3) * 16;
    const float* wsrc = W + ((size_t)c << 16) + (size_t)(kb * 64 + r) * 256 + hb * 64 + cg;

    const int wid  = tid >> 6;
    const int lane = tid & 63;
    const int s = bid * 4 + wid;              // 0..4095 exact cover
    const float* xsrc = x + ((size_t)s << 12);
    _Float16* xdst = x16 + ((size_t)s << 12);
    const int cc = lane << 2;                 // float col 0..252
    const int slot = lane >> 1;               // 16B slot 0..31
    const int lo = cc & 7;

    // ---- issue W loads (4 x float4) ----
    float4 wv[4];
#pragma unroll
    for (int j = 0; j < 4; j++) wv[j] = *(const float4*)(wsrc + j * 4);

    // ---- issue x batch A (rows 0..7, 8 x float4) ----
    float4 xa[8];
#pragma unroll
    for (int j = 0; j < 8; j++) xa[j] = *(const float4*)(xsrc + j * 256 + cc);

    // ---- W -> LDS (waits only on wv) ----
#pragma unroll
    for (int j = 0; j < 4; j++) {
      t[r][cg + j * 4 + 0] = (_Float16)wv[j].x;
      t[r][cg + j * 4 + 1] = (_Float16)wv[j].y;
      t[r][cg + j * 4 + 2] = (_Float16)wv[j].z;
      t[r][cg + j * 4 + 3] = (_Float16)wv[j].w;
    }
    __syncthreads();

    // ---- issue x batch B (rows 8..15) BEFORE draining batch A ----
    float4 xb[8];
#pragma unroll
    for (int j = 0; j < 8; j++) xb[j] = *(const float4*)(xsrc + (8 + j) * 256 + cc);

    // ---- cvt + store batch A (swizzle: slot' = slot ^ (row&7); (8+j)&7==j&7) ----
#pragma unroll
    for (int j = 0; j < 8; j++) {
      half4 h;
      h[0] = (_Float16)xa[j].x; h[1] = (_Float16)xa[j].y;
      h[2] = (_Float16)xa[j].z; h[3] = (_Float16)xa[j].w;
      *(half4*)(xdst + j * 256 + (((slot ^ (j & 7)) << 3) | lo)) = h;
    }

    // ---- Wt store from LDS ----
    _Float16* dst = Wt + ((size_t)c << 16) + (size_t)(hb * 64 + r) * 256 + kb * 64 + cg;
    half8 o0, o1;
#pragma unroll
    for (int j = 0; j < 8; j++) o0[j] = t[cg + j][r];
#pragma unroll
    for (int j = 0; j < 8; j++) o1[j] = t[cg + 8 + j][r];
    *(half8*)(dst) = o0;
    *(half8*)(dst + 8) = o1;

    // ---- cvt + store batch B ----
#pragma unroll
    for (int j = 0; j < 8; j++) {
      half4 h;
      h[0] = (_Float16)xb[j].x; h[1] = (_Float16)xb[j].y;
      h[2] = (_Float16)xb[j].z; h[3] = (_Float16)xb[j].w;
      *(half4*)(xdst + (8 + j) * 256 + (((slot ^ (j & 7)) << 3) | lo)) = h;
    }
  } else {
    __shared__ int hist[N_CATS];
    __shared__ int poffs[N_CATS];
    __shared__ int curs[N_CATS];
    if (tid < N_CATS) hist[tid] = 0;
    for (int i = tid; i < MAX_PADDED; i += 256) ord[i] = -1;
    for (int i = tid; i < NGROUP; i += 256) gcat[i] = 0;
    __syncthreads();
    for (int i = tid; i < N_SAMPLES; i += 256) atomicAdd(&hist[cat[i]], 1);
    __syncthreads();
    if (tid == 0) {
      int run = 0;
      for (int c = 0; c < N_CATS; c++) {
        poffs[c] = run;
        run += ((hist[c] + SPB - 1) / SPB) * SPB;
      }
    }
    if (tid < N_CATS) curs[tid] = 0;
    __syncthreads();
    if (tid < N_CATS) {
      const int c = tid;
      const int g0 = poffs[c] >> 2;
      const int ng = (hist[c] + SPB - 1) >> 2;
      for (int g = 0; g < ng; g++) gcat[g0 + g] = c;
    }
    for (int i = tid; i < N_SAMPLES; i += 256) {
      int c = cat[i];
      int p = poffs[c] + atomicAdd(&curs[c], 1);
      ord[p] = i;
    }
  }
}

// ---------------- main GEMM (R11 body, unchanged) ----------------
__global__ __launch_bounds__(256, 5)
void gemm_dma(const _Float16* __restrict__ x16, const float* __restrict__ bias,
              const _Float16* __restrict__ Wt, const int* __restrict__ ord,
              const int* __restrict__ gcat, float* __restrict__ out) {
  __shared__ __align__(16) _Float16 sA[64 * 256];  // 32 KB

  const int tid = threadIdx.x;
  const int B = blockIdx.x;
  const int xcd = B & 7;
  const int slot = B >> 3;
  const int h_half = slot & 1;
  const int group = xcd * GPX + (slot >> 1);
  const int h0 = h_half << 7;

  const int cat = gcat[group];
  const int4 sm = *(const int4*)(ord + group * 4);
  if (sm.x < 0) return;

  const int wid  = tid >> 6;
  const int lane = tid & 63;
  const int l15  = lane & 15;
  const int quad = lane >> 4;

  const _Float16* wb = Wt + ((size_t)cat << 16) +
                       (size_t)(h0 + wid * 32 + l15) * K_DIM + quad * 8;

  // ---- B fragments kt=0..3 into slots 0..3 + bias: issue FIRST ----
  half8 bf[5][2];
#pragma unroll
  for (int kt = 0; kt < 4; kt++) {
    bf[kt][0] = *(const half8*)(wb + kt * 32);
    bf[kt][1] = *(const half8*)(wb + 16 * K_DIM + kt * 32);
  }
  const float bv0 = bias[cat * H_DIM + h0 + wid * 32 + l15];
  const float bv1 = bias[cat * H_DIM + h0 + wid * 32 + 16 + l15];
  __builtin_amdgcn_sched_barrier(0);

  // ---- A staging: wave w DMAs its sample (8 x 1KB, linear dest) ----
  const int smp0 = (wid == 0) ? sm.x : (wid == 1) ? sm.y : (wid == 2) ? sm.z : sm.w;
  const int smp  = (smp0 >= 0) ? smp0 : sm.x;  // padded rows: junk, never stored
  const _Float16* asrc = x16 + ((size_t)smp << 12) + (lane << 3);
  _Float16* adst = sA + wid * 4096;
#pragma unroll
  for (int i = 0; i < 8; i++)
    GLOAD_LDS(asrc + i * 512, adst + i * 512);

  floatx4 acc[4][2];
#pragma unroll
  for (int i = 0; i < 4; i++)
#pragma unroll
    for (int j = 0; j < 2; j++)
#pragma unroll
      for (int e = 0; e < 4; e++) acc[i][j][e] = 0.0f;

  __syncthreads();  // the ONLY barrier (vmcnt(0) drain completes DMA + bf kt0-3)

  // ---- MFMA loop: 5-slot rotating B prefetch; swizzled conflict-free A reads ----
#pragma unroll
  for (int kt = 0; kt < 8; kt++) {
    if (kt < 4) {
      bf[(kt + 4) % 5][0] = *(const half8*)(wb + (kt + 4) * 32);
      bf[(kt + 4) % 5][1] = *(const half8*)(wb + 16 * K_DIM + (kt + 4) * 32);
      __builtin_amdgcn_sched_barrier(0);
    }
    half8 af[4];
#pragma unroll
    for (int mt = 0; mt < 4; mt++)
      af[mt] = *(const half8*)&sA[(size_t)(mt * 16 + l15) * 256 +
                                  (((kt * 4 + quad) ^ (l15 & 7)) << 3)];
#pragma unroll
    for (int mt = 0; mt < 4; mt++) {
      acc[mt][0] = __builtin_amdgcn_mfma_f32_16x16x32_f16(af[mt], bf[kt % 5][0], acc[mt][0], 0, 0, 0);
      acc[mt][1] = __builtin_amdgcn_mfma_f32_16x16x32_f16(af[mt], bf[kt % 5][1], acc[mt][1], 0, 0, 0);
    }
  }

  // ---- epilogue: C/D layout col=lane&15, row=quad*4+reg ----
  const int srow[4] = {sm.x, sm.y, sm.z, sm.w};
#pragma unroll
  for (int mt = 0; mt < 4; mt++) {
    const int s = srow[mt];
    if (s < 0) continue;
    float* obase = out + ((size_t)s << 12);
#pragma unroll
    for (int nt = 0; nt < 2; nt++) {
      const int col = h0 + wid * 32 + nt * 16 + l15;
      const float bv = nt ? bv1 : bv0;
#pragma unroll
      for (int rr = 0; rr < 4; rr++) {
        const int row = quad * 4 + rr;
        obase[(size_t)row * H_DIM + col] = acc[mt][nt][rr] + bv;
      }
    }
  }
}

// ---------------- small-tier GEMM (reg-staged A) ----------------
__global__ __launch_bounds__(256, 3)
void gemm_small(const float* __restrict__ x, const float* __restrict__ bias,
                const _Float16* __restrict__ Wt, const int* __restrict__ ord,
                const int* __restrict__ gcat, float* __restrict__ out) {
  __shared__ __align__(16) _Float16 sA[64 * AROW];

  const int tid = threadIdx.x;
  const int B = blockIdx.x;
  const int xcd = B & 7;
  const int slot = B >> 3;
  const int h_half = slot & 1;
  const int group = xcd * GPX + (slot >> 1);
  const int h0 = h_half << 7;

  const int cat = gcat[group];
  const int4 sm = *(const int4*)(ord + group * 4);
  if (sm.x < 0) return;

  const int wid  = tid >> 6;
  const int lane = tid & 63;
  const int l15  = lane & 15;
  const int quad = lane >> 4;

  const _Float16* wb = Wt + ((size_t)cat << 16) +
                       (size_t)(h0 + wid * 32 + l15) * K_DIM + quad * 8;

  half8 bf[5][2];
#pragma unroll
  for (int kt = 0; kt < 4; kt++) {
    bf[kt][0] = *(const half8*)(wb + kt * 32);
    bf[kt][1] = *(const half8*)(wb + 16 * K_DIM + kt * 32);
  }
  const float bv0 = bias[cat * H_DIM + h0 + wid * 32 + l15];
  const float bv1 = bias[cat * H_DIM + h0 + wid * 32 + 16 + l15];
  __builtin_amdgcn_sched_barrier(0);

  const int smp = (wid == 0) ? sm.x : (wid == 1) ? sm.y : (wid == 2) ? sm.z : sm.w;
  const float* asrc = (smp >= 0) ? (x + ((size_t)smp << 12)) : nullptr;
  _Float16* adst = sA + (size_t)(wid * 16) * AROW;
  if (asrc) {
#pragma unroll
    for (int j = 0; j < 16; j++) {
      float4 v = *(const float4*)(asrc + j * 256 + lane * 4);
      half4 h;
      h[0] = (_Float16)v.x; h[1] = (_Float16)v.y;
      h[2] = (_Float16)v.z; h[3] = (_Float16)v.w;
      *(half4*)(adst + (size_t)j * AROW + lane * 4) = h;
    }
  } else {
    half4 h;
#pragma unroll
    for (int e = 0; e < 4; e++) h[e] = (_Float16)0.0f;
#pragma unroll
    for (int j = 0; j < 16; j++)
      *(half4*)(adst + (size_t)j * AROW + lane * 4) = h;
  }

  floatx4 acc[4][2];
#pragma unroll
  for (int i = 0; i < 4; i++)
#pragma unroll
    for (int j = 0; j < 2; j++)
#pragma unroll
      for (int e = 0; e < 4; e++) acc[i][j][e] = 0.0f;

  __syncthreads();

#pragma unroll
  for (int kt = 0; kt < 8; kt++) {
    if (kt < 4) {
      bf[(kt + 4) % 5][0] = *(const half8*)(wb + (kt + 4) * 32);
      bf[(kt + 4) % 5][1] = *(const half8*)(wb + 16 * K_DIM + (kt + 4) * 32);
      __builtin_amdgcn_sched_barrier(0);
    }
    half8 af[4];
#pragma unroll
    for (int mt = 0; mt < 4; mt++)
      af[mt] = *(const half8*)&sA[(size_t)(mt * 16 + l15) * AROW + kt * 32 + quad * 8];
#pragma unroll
    for (int mt = 0; mt < 4; mt++) {
      acc[mt][0] = __builtin_amdgcn_mfma_f32_16x16x32_f16(af[mt], bf[kt % 5][0], acc[mt][0], 0, 0, 0);
      acc[mt][1] = __builtin_amdgcn_mfma_f32_16x16x32_f16(af[mt], bf[kt % 5][1], acc[mt][1], 0, 0, 0);
    }
  }

  const int srow[4] = {sm.x, sm.y, sm.z, sm.w};
#pragma unroll
  for (int mt = 0; mt < 4; mt++) {
    const int s = srow[mt];
    if (s < 0) continue;
    float* obase = out + ((size_t)s << 12);
#pragma unroll
    for (int nt = 0; nt < 2; nt++) {
      const int col = h0 + wid * 32 + nt * 16 + l15;
      const float bv = nt ? bv1 : bv0;
#pragma unroll
      for (int rr = 0; rr < 4; rr++) {
        const int row = quad * 4 + rr;
        obase[(size_t)row * H_DIM + col] = acc[mt][nt][rr] + bv;
      }
    }
  }
}

// ---------------- fallback (ws too small): naive fp32 ----------------
__global__ __launch_bounds__(256)
void naive_kernel(const float* __restrict__ x, const int* __restrict__ cat,
                  const float* __restrict__ W, const float* __restrict__ bias,
                  float* __restrict__ out) {
  __shared__ float sx[16 * 256];
  const int n = blockIdx.x;
  const int tid = threadIdx.x;
  const int c = cat[n];
  const float* xs = x + (size_t)n * 16 * 256;
  for (int i = tid; i < 16 * 256; i += 256) sx[i] = xs[i];
  __syncthreads();
  const float* Wc = W + ((size_t)c << 16);
  float accv[16];
  float bv = bias[c * 256 + tid];
#pragma unroll
  for (int m = 0; m < 16; m++) accv[m] = bv;
  for (int k = 0; k < 256; k++) {
    float w = Wc[(size_t)k * 256 + tid];
#pragma unroll
    for (int m = 0; m < 16; m++) accv[m] += sx[m * 256 + k] * w;
  }
#pragma unroll
  for (int m = 0; m < 16; m++) out[((size_t)n * 16 + m) * 256 + tid] = accv[m];
}

// ---------------- launcher ----------------
extern "C" void kernel_launch(void* const* d_in, const int* in_sizes, int n_in,
                              void* d_out, int out_size, void* d_ws, size_t ws_size,
                              hipStream_t stream) {
  const float* x    = (const float*)d_in[0];
  const int*   cat  = (const int*)d_in[1];
  const float* W    = (const float*)d_in[2];
  const float* bias = (const float*)d_in[3];
  float* out = (float*)d_out;

  char* ws = (char*)d_ws;
  if (ws_size >= WS_NEED_F) {
    _Float16* Wt  = (_Float16*)ws;
    _Float16* x16 = (_Float16*)(ws + WT_BYTES);
    int* gcat = (int*)(ws + GCAT_OFF_F);
    int* ord  = (int*)(ws + ORD_OFF_F);
    prep_combined<<<1025, 256, 0, stream>>>(W, Wt, cat, ord, gcat, x, x16);
    gemm_dma<<<GEMM_GRID, 256, 0, stream>>>(x16, bias, Wt, ord, gcat, out);
  } else if (ws_size >= WS_NEED_S) {
    _Float16* Wt = (_Float16*)ws;
    int* gcat = (int*)(ws + GCAT_OFF_S);
    int* ord  = (int*)(ws + ORD_OFF_S);
    prep_combined<<<1025, 256, 0, stream>>>(W, Wt, cat, ord, gcat, x, nullptr);
    gemm_small<<<GEMM_GRID, 256, 0, stream>>>(x, bias, Wt, ord, gcat, out);
  } else {
    naive_kernel<<<N_SAMPLES, 256, 0, stream>>>(x, cat, W, bias, out);
  }
}

// Round 13
// 162.591 us; speedup vs baseline: 1.0040x; 1.0040x over previous
//
#include <hip/hip_runtime.h>
#include <hip/hip_bf16.h>
#include <stdint.h>

#define N_SAMPLES 4096
#define M_ROWS 16
#define K_DIM 256
#define H_DIM 256
#define N_CATS 64
#define SPB 4                                        // samples per group (64 rows)
#define MAX_PADDED (N_SAMPLES + N_CATS * (SPB - 1))  // 4288
#define NGROUP (MAX_PADDED / SPB)                    // 1072
#define GPX (NGROUP / 8)                             // 134 groups per XCD
#define GEMM_GRID (NGROUP * 2)                       // 2144 units (group x h-half)
#define AROW 264                                     // small-tier fallback layout

typedef _Float16 half8 __attribute__((ext_vector_type(8)));
typedef _Float16 half4 __attribute__((ext_vector_type(4)));
typedef float floatx4 __attribute__((ext_vector_type(4)));

// async global->LDS DMA, 16B per lane (dest = uniform base + lane*16)
#define GLOAD_LDS(g, l)                                          \
  __builtin_amdgcn_global_load_lds(                              \
      (const __attribute__((address_space(1))) void*)(g),        \
      (__attribute__((address_space(3))) void*)(l), 16, 0, 0)

// ---- workspace layout ----
// full tier: Wt (8MB) | x16 (32MB, swizzled f16) | gcat | ord
#define WT_BYTES  ((size_t)N_CATS * K_DIM * H_DIM * 2)
#define X16_BYTES ((size_t)N_SAMPLES * M_ROWS * K_DIM * 2)
#define GCAT_OFF_F (WT_BYTES + X16_BYTES)
#define ORD_OFF_F  (GCAT_OFF_F + 4288)
#define WS_NEED_F  (ORD_OFF_F + (size_t)MAX_PADDED * 4)
// small tier (no x16): Wt | gcat | ord
#define GCAT_OFF_S WT_BYTES
#define ORD_OFF_S  (WT_BYTES + 4288)
#define WS_NEED_S  (ORD_OFF_S + (size_t)MAX_PADDED * 4)

// ---------------- balanced prep: 1025 blocks, PINNED deep load pipeline ----------------
// R12 post-mortem: source-level batching did NOT claim registers (VGPR stayed
// 36) -- the scheduler re-sank the loads. Fix (proven in the gemm): issue ALL
// 20 float4 loads (4 W + 16 x rows) up front, then sched_barrier(0) so they
// CANNOT sink. 80 VGPRs in flight, live ~95 < 128 budget (256,4).
// Consumption is oldest-first: W->LDS -> sync -> x rows 0-7 -> Wt -> rows 8-15.
// Addresses/swizzle identical to R11/R12 (numerics unchanged).
__global__ __launch_bounds__(256, 4)
void prep_combined(const float* __restrict__ W, _Float16* __restrict__ Wt,
                   const int* __restrict__ cat, int* __restrict__ ord,
                   int* __restrict__ gcat,
                   const float* __restrict__ x, _Float16* __restrict__ x16) {
  const int tid = threadIdx.x;
  const int bid = blockIdx.x;
  if (bid < 1024) {
    __shared__ _Float16 t[64][72];
    const int c  = bid >> 4;
    const int kb = (bid >> 2) & 3;
    const int hb = bid & 3;
    const int r  = tid >> 2;
    const int cg = (tid & 3) * 16;
    const float* wsrc = W + ((size_t)c << 16) + (size_t)(kb * 64 + r) * 256 + hb * 64 + cg;

    const int wid  = tid >> 6;
    const int lane = tid & 63;
    const int s = bid * 4 + wid;              // 0..4095 exact cover
    const float* xsrc = x + ((size_t)s << 12);
    _Float16* xdst = x16 + ((size_t)s << 12);
    const int cc = lane << 2;                 // float col 0..252
    const int slot = lane >> 1;               // 16B slot 0..31
    const int lo = cc & 7;

    // ---- issue ALL loads up front: 4 W + 16 x rows (80 VGPRs in flight) ----
    float4 wv[4];
#pragma unroll
    for (int j = 0; j < 4; j++) wv[j] = *(const float4*)(wsrc + j * 4);
    float4 xa[8], xb[8];
#pragma unroll
    for (int j = 0; j < 8; j++) xa[j] = *(const float4*)(xsrc + j * 256 + cc);
#pragma unroll
    for (int j = 0; j < 8; j++) xb[j] = *(const float4*)(xsrc + (8 + j) * 256 + cc);
    __builtin_amdgcn_sched_barrier(0);  // PIN: loads may not sink below here

    // ---- W -> LDS (waits only on wv, the oldest 4 loads) ----
#pragma unroll
    for (int j = 0; j < 4; j++) {
      t[r][cg + j * 4 + 0] = (_Float16)wv[j].x;
      t[r][cg + j * 4 + 1] = (_Float16)wv[j].y;
      t[r][cg + j * 4 + 2] = (_Float16)wv[j].z;
      t[r][cg + j * 4 + 3] = (_Float16)wv[j].w;
    }
    __syncthreads();

    // ---- cvt + store x rows 0..7 (swizzle: slot' = slot ^ (row&7)) ----
#pragma unroll
    for (int j = 0; j < 8; j++) {
      half4 h;
      h[0] = (_Float16)xa[j].x; h[1] = (_Float16)xa[j].y;
      h[2] = (_Float16)xa[j].z; h[3] = (_Float16)xa[j].w;
      *(half4*)(xdst + j * 256 + (((slot ^ (j & 7)) << 3) | lo)) = h;
    }

    // ---- Wt store from LDS ----
    _Float16* dst = Wt + ((size_t)c << 16) + (size_t)(hb * 64 + r) * 256 + kb * 64 + cg;
    half8 o0, o1;
#pragma unroll
    for (int j = 0; j < 8; j++) o0[j] = t[cg + j][r];
#pragma unroll
    for (int j = 0; j < 8; j++) o1[j] = t[cg + 8 + j][r];
    *(half8*)(dst) = o0;
    *(half8*)(dst + 8) = o1;

    // ---- cvt + store x rows 8..15 ((8+j)&7 == j&7) ----
#pragma unroll
    for (int j = 0; j < 8; j++) {
      half4 h;
      h[0] = (_Float16)xb[j].x; h[1] = (_Float16)xb[j].y;
      h[2] = (_Float16)xb[j].z; h[3] = (_Float16)xb[j].w;
      *(half4*)(xdst + (8 + j) * 256 + (((slot ^ (j & 7)) << 3) | lo)) = h;
    }
  } else {
    __shared__ int hist[N_CATS];
    __shared__ int poffs[N_CATS];
    __shared__ int curs[N_CATS];
    if (tid < N_CATS) hist[tid] = 0;
    for (int i = tid; i < MAX_PADDED; i += 256) ord[i] = -1;
    for (int i = tid; i < NGROUP; i += 256) gcat[i] = 0;
    __syncthreads();
    for (int i = tid; i < N_SAMPLES; i += 256) atomicAdd(&hist[cat[i]], 1);
    __syncthreads();
    if (tid == 0) {
      int run = 0;
      for (int c = 0; c < N_CATS; c++) {
        poffs[c] = run;
        run += ((hist[c] + SPB - 1) / SPB) * SPB;
      }
    }
    if (tid < N_CATS) curs[tid] = 0;
    __syncthreads();
    if (tid < N_CATS) {
      const int c = tid;
      const int g0 = poffs[c] >> 2;
      const int ng = (hist[c] + SPB - 1) >> 2;
      for (int g = 0; g < ng; g++) gcat[g0 + g] = c;
    }
    for (int i = tid; i < N_SAMPLES; i += 256) {
      int c = cat[i];
      int p = poffs[c] + atomicAdd(&curs[c], 1);
      ord[p] = i;
    }
  }
}

// ---------------- main GEMM (R11 body, unchanged) ----------------
__global__ __launch_bounds__(256, 5)
void gemm_dma(const _Float16* __restrict__ x16, const float* __restrict__ bias,
              const _Float16* __restrict__ Wt, const int* __restrict__ ord,
              const int* __restrict__ gcat, float* __restrict__ out) {
  __shared__ __align__(16) _Float16 sA[64 * 256];  // 32 KB

  const int tid = threadIdx.x;
  const int B = blockIdx.x;
  const int xcd = B & 7;
  const int slot = B >> 3;
  const int h_half = slot & 1;
  const int group = xcd * GPX + (slot >> 1);
  const int h0 = h_half << 7;

  const int cat = gcat[group];
  const int4 sm = *(const int4*)(ord + group * 4);
  if (sm.x < 0) return;

  const int wid  = tid >> 6;
  const int lane = tid & 63;
  const int l15  = lane & 15;
  const int quad = lane >> 4;

  const _Float16* wb = Wt + ((size_t)cat << 16) +
                       (size_t)(h0 + wid * 32 + l15) * K_DIM + quad * 8;

  // ---- B fragments kt=0..3 into slots 0..3 + bias: issue FIRST ----
  half8 bf[5][2];
#pragma unroll
  for (int kt = 0; kt < 4; kt++) {
    bf[kt][0] = *(const half8*)(wb + kt * 32);
    bf[kt][1] = *(const half8*)(wb + 16 * K_DIM + kt * 32);
  }
  const float bv0 = bias[cat * H_DIM + h0 + wid * 32 + l15];
  const float bv1 = bias[cat * H_DIM + h0 + wid * 32 + 16 + l15];
  __builtin_amdgcn_sched_barrier(0);

  // ---- A staging: wave w DMAs its sample (8 x 1KB, linear dest) ----
  const int smp0 = (wid == 0) ? sm.x : (wid == 1) ? sm.y : (wid == 2) ? sm.z : sm.w;
  const int smp  = (smp0 >= 0) ? smp0 : sm.x;  // padded rows: junk, never stored
  const _Float16* asrc = x16 + ((size_t)smp << 12) + (lane << 3);
  _Float16* adst = sA + wid * 4096;
#pragma unroll
  for (int i = 0; i < 8; i++)
    GLOAD_LDS(asrc + i * 512, adst + i * 512);

  floatx4 acc[4][2];
#pragma unroll
  for (int i = 0; i < 4; i++)
#pragma unroll
    for (int j = 0; j < 2; j++)
#pragma unroll
      for (int e = 0; e < 4; e++) acc[i][j][e] = 0.0f;

  __syncthreads();  // the ONLY barrier (vmcnt(0) drain completes DMA + bf kt0-3)

  // ---- MFMA loop: 5-slot rotating B prefetch; swizzled conflict-free A reads ----
#pragma unroll
  for (int kt = 0; kt < 8; kt++) {
    if (kt < 4) {
      bf[(kt + 4) % 5][0] = *(const half8*)(wb + (kt + 4) * 32);
      bf[(kt + 4) % 5][1] = *(const half8*)(wb + 16 * K_DIM + (kt + 4) * 32);
      __builtin_amdgcn_sched_barrier(0);
    }
    half8 af[4];
#pragma unroll
    for (int mt = 0; mt < 4; mt++)
      af[mt] = *(const half8*)&sA[(size_t)(mt * 16 + l15) * 256 +
                                  (((kt * 4 + quad) ^ (l15 & 7)) << 3)];
#pragma unroll
    for (int mt = 0; mt < 4; mt++) {
      acc[mt][0] = __builtin_amdgcn_mfma_f32_16x16x32_f16(af[mt], bf[kt % 5][0], acc[mt][0], 0, 0, 0);
      acc[mt][1] = __builtin_amdgcn_mfma_f32_16x16x32_f16(af[mt], bf[kt % 5][1], acc[mt][1], 0, 0, 0);
    }
  }

  // ---- epilogue: C/D layout col=lane&15, row=quad*4+reg ----
  const int srow[4] = {sm.x, sm.y, sm.z, sm.w};
#pragma unroll
  for (int mt = 0; mt < 4; mt++) {
    const int s = srow[mt];
    if (s < 0) continue;
    float* obase = out + ((size_t)s << 12);
#pragma unroll
    for (int nt = 0; nt < 2; nt++) {
      const int col = h0 + wid * 32 + nt * 16 + l15;
      const float bv = nt ? bv1 : bv0;
#pragma unroll
      for (int rr = 0; rr < 4; rr++) {
        const int row = quad * 4 + rr;
        obase[(size_t)row * H_DIM + col] = acc[mt][nt][rr] + bv;
      }
    }
  }
}

// ---------------- small-tier GEMM (reg-staged A) ----------------
__global__ __launch_bounds__(256, 3)
void gemm_small(const float* __restrict__ x, const float* __restrict__ bias,
                const _Float16* __restrict__ Wt, const int* __restrict__ ord,
                const int* __restrict__ gcat, float* __restrict__ out) {
  __shared__ __align__(16) _Float16 sA[64 * AROW];

  const int tid = threadIdx.x;
  const int B = blockIdx.x;
  const int xcd = B & 7;
  const int slot = B >> 3;
  const int h_half = slot & 1;
  const int group = xcd * GPX + (slot >> 1);
  const int h0 = h_half << 7;

  const int cat = gcat[group];
  const int4 sm = *(const int4*)(ord + group * 4);
  if (sm.x < 0) return;

  const int wid  = tid >> 6;
  const int lane = tid & 63;
  const int l15  = lane & 15;
  const int quad = lane >> 4;

  const _Float16* wb = Wt + ((size_t)cat << 16) +
                       (size_t)(h0 + wid * 32 + l15) * K_DIM + quad * 8;

  half8 bf[5][2];
#pragma unroll
  for (int kt = 0; kt < 4; kt++) {
    bf[kt][0] = *(const half8*)(wb + kt * 32);
    bf[kt][1] = *(const half8*)(wb + 16 * K_DIM + kt * 32);
  }
  const float bv0 = bias[cat * H_DIM + h0 + wid * 32 + l15];
  const float bv1 = bias[cat * H_DIM + h0 + wid * 32 + 16 + l15];
  __builtin_amdgcn_sched_barrier(0);

  const int smp = (wid == 0) ? sm.x : (wid == 1) ? sm.y : (wid == 2) ? sm.z : sm.w;
  const float* asrc = (smp >= 0) ? (x + ((size_t)smp << 12)) : nullptr;
  _Float16* adst = sA + (size_t)(wid * 16) * AROW;
  if (asrc) {
#pragma unroll
    for (int j = 0; j < 16; j++) {
      float4 v = *(const float4*)(asrc + j * 256 + lane * 4);
      half4 h;
      h[0] = (_Float16)v.x; h[1] = (_Float16)v.y;
      h[2] = (_Float16)v.z; h[3] = (_Float16)v.w;
      *(half4*)(adst + (size_t)j * AROW + lane * 4) = h;
    }
  } else {
    half4 h;
#pragma unroll
    for (int e = 0; e < 4; e++) h[e] = (_Float16)0.0f;
#pragma unroll
    for (int j = 0; j < 16; j++)
      *(half4*)(adst + (size_t)j * AROW + lane * 4) = h;
  }

  floatx4 acc[4][2];
#pragma unroll
  for (int i = 0; i < 4; i++)
#pragma unroll
    for (int j = 0; j < 2; j++)
#pragma unroll
      for (int e = 0; e < 4; e++) acc[i][j][e] = 0.0f;

  __syncthreads();

#pragma unroll
  for (int kt = 0; kt < 8; kt++) {
    if (kt < 4) {
      bf[(kt + 4) % 5][0] = *(const half8*)(wb + (kt + 4) * 32);
      bf[(kt + 4) % 5][1] = *(const half8*)(wb + 16 * K_DIM + (kt + 4) * 32);
      __builtin_amdgcn_sched_barrier(0);
    }
    half8 af[4];
#pragma unroll
    for (int mt = 0; mt < 4; mt++)
      af[mt] = *(const half8*)&sA[(size_t)(mt * 16 + l15) * AROW + kt * 32 + quad * 8];
#pragma unroll
    for (int mt = 0; mt < 4; mt++) {
      acc[mt][0] = __builtin_amdgcn_mfma_f32_16x16x32_f16(af[mt], bf[kt % 5][0], acc[mt][0], 0, 0, 0);
      acc[mt][1] = __builtin_amdgcn_mfma_f32_16x16x32_f16(af[mt], bf[kt % 5][1], acc[mt][1], 0, 0, 0);
    }
  }

  const int srow[4] = {sm.x, sm.y, sm.z, sm.w};
#pragma unroll
  for (int mt = 0; mt < 4; mt++) {
    const int s = srow[mt];
    if (s < 0) continue;
    float* obase = out + ((size_t)s << 12);
#pragma unroll
    for (int nt = 0; nt < 2; nt++) {
      const int col = h0 + wid * 32 + nt * 16 + l15;
      const float bv = nt ? bv1 : bv0;
#pragma unroll
      for (int rr = 0; rr < 4; rr++) {
        const int row = quad * 4 + rr;
        obase[(size_t)row * H_DIM + col] = acc[mt][nt][rr] + bv;
      }
    }
  }
}

// ---------------- fallback (ws too small): naive fp32 ----------------
__global__ __launch_bounds__(256)
void naive_kernel(const float* __restrict__ x, const int* __restrict__ cat,
                  const float* __restrict__ W, const float* __restrict__ bias,
                  float* __restrict__ out) {
  __shared__ float sx[16 * 256];
  const int n = blockIdx.x;
  const int tid = threadIdx.x;
  const int c = cat[n];
  const float* xs = x + (size_t)n * 16 * 256;
  for (int i = tid; i < 16 * 256; i += 256) sx[i] = xs[i];
  __syncthreads();
  const float* Wc = W + ((size_t)c << 16);
  float accv[16];
  float bv = bias[c * 256 + tid];
#pragma unroll
  for (int m = 0; m < 16; m++) accv[m] = bv;
  for (int k = 0; k < 256; k++) {
    float w = Wc[(size_t)k * 256 + tid];
#pragma unroll
    for (int m = 0; m < 16; m++) accv[m] += sx[m * 256 + k] * w;
  }
#pragma unroll
  for (int m = 0; m < 16; m++) out[((size_t)n * 16 + m) * 256 + tid] = accv[m];
}

// ---------------- launcher ----------------
extern "C" void kernel_launch(void* const* d_in, const int* in_sizes, int n_in,
                              void* d_out, int out_size, void* d_ws, size_t ws_size,
                              hipStream_t stream) {
  const float* x    = (const float*)d_in[0];
  const int*   cat  = (const int*)d_in[1];
  const float* W    = (const float*)d_in[2];
  const float* bias = (const float*)d_in[3];
  float* out = (float*)d_out;

  char* ws = (char*)d_ws;
  if (ws_size >= WS_NEED_F) {
    _Float16* Wt  = (_Float16*)ws;
    _Float16* x16 = (_Float16*)(ws + WT_BYTES);
    int* gcat = (int*)(ws + GCAT_OFF_F);
    int* ord  = (int*)(ws + ORD_OFF_F);
    prep_combined<<<1025, 256, 0, stream>>>(W, Wt, cat, ord, gcat, x, x16);
    gemm_dma<<<GEMM_GRID, 256, 0, stream>>>(x16, bias, Wt, ord, gcat, out);
  } else if (ws_size >= WS_NEED_S) {
    _Float16* Wt = (_Float16*)ws;
    int* gcat = (int*)(ws + GCAT_OFF_S);
    int* ord  = (int*)(ws + ORD_OFF_S);
    prep_combined<<<1025, 256, 0, stream>>>(W, Wt, cat, ord, gcat, x, nullptr);
    gemm_small<<<GEMM_GRID, 256, 0, stream>>>(x, cat ? bias : bias, Wt, ord, gcat, out);
  } else {
    naive_kernel<<<N_SAMPLES, 256, 0, stream>>>(x, cat, W, bias, out);
  }
}

// Round 14
// 154.390 us; speedup vs baseline: 1.0574x; 1.0531x over previous
//
#include <hip/hip_runtime.h>
#include <hip/hip_bf16.h>
#include <stdint.h>

#define N_SAMPLES 4096
#define M_ROWS 16
#define K_DIM 256
#define H_DIM 256
#define N_CATS 64
#define SPB 4                                        // samples per group (64 rows)
#define MAX_PADDED (N_SAMPLES + N_CATS * (SPB - 1))  // 4288
#define NGROUP (MAX_PADDED / SPB)                    // 1072
#define GPX (NGROUP / 8)                             // 134 groups per XCD
#define GEMM_GRID (NGROUP * 2)                       // 2144 units (group x h-half)
#define AROW 264                                     // small-tier fallback layout

typedef _Float16 half8 __attribute__((ext_vector_type(8)));
typedef _Float16 half4 __attribute__((ext_vector_type(4)));
typedef float floatx4 __attribute__((ext_vector_type(4)));

// async global->LDS DMA, 16B per lane (dest = uniform base + lane*16)
#define GLOAD_LDS(g, l)                                          \
  __builtin_amdgcn_global_load_lds(                              \
      (const __attribute__((address_space(1))) void*)(g),        \
      (__attribute__((address_space(3))) void*)(l), 16, 0, 0)

// ---- workspace layout ----
// full tier: Wt (8MB) | x16 (32MB, swizzled f16) | gcat | ord
#define WT_BYTES  ((size_t)N_CATS * K_DIM * H_DIM * 2)
#define X16_BYTES ((size_t)N_SAMPLES * M_ROWS * K_DIM * 2)
#define GCAT_OFF_F (WT_BYTES + X16_BYTES)
#define ORD_OFF_F  (GCAT_OFF_F + 4288)
#define WS_NEED_F  (ORD_OFF_F + (size_t)MAX_PADDED * 4)
// small tier (no x16): Wt | gcat | ord
#define GCAT_OFF_S WT_BYTES
#define ORD_OFF_S  (WT_BYTES + 4288)
#define WS_NEED_S  (ORD_OFF_S + (size_t)MAX_PADDED * 4)

// ---------------- balanced prep: 1025 blocks ----------------
// R13 post-mortem: prep dur (~48us) is INVARIANT under all W/x-copy changes
// -> the single bucketing block is the straggler: ~32 serialized rounds of
// {cold global cat[i] load -> LDS atomic -> store} at ~1us each while the
// 1024 copy blocks finish early.
// Fix: bulk-load all 4096 cat ids into LDS FIRST (4 x int4/thread, issued
// before the ord/gcat init stores so the latency hides under them), then
// run hist/prefix/scatter entirely out of LDS -> zero global-load latency
// in the inner rounds.
// W/x copy branch: R12's version (its best measurement, 42us).
__global__ __launch_bounds__(256, 4)
void prep_combined(const float* __restrict__ W, _Float16* __restrict__ Wt,
                   const int* __restrict__ cat, int* __restrict__ ord,
                   int* __restrict__ gcat,
                   const float* __restrict__ x, _Float16* __restrict__ x16) {
  const int tid = threadIdx.x;
  const int bid = blockIdx.x;
  if (bid < 1024) {
    __shared__ _Float16 t[64][72];
    const int c  = bid >> 4;
    const int kb = (bid >> 2) & 3;
    const int hb = bid & 3;
    const int r  = tid >> 2;
    const int cg = (tid & 3) * 16;
    const float* wsrc = W + ((size_t)c << 16) + (size_t)(kb * 64 + r) * 256 + hb * 64 + cg;

    const int wid  = tid >> 6;
    const int lane = tid & 63;
    const int s = bid * 4 + wid;              // 0..4095 exact cover
    const float* xsrc = x + ((size_t)s << 12);
    _Float16* xdst = x16 + ((size_t)s << 12);
    const int cc = lane << 2;                 // float col 0..252
    const int slot = lane >> 1;               // 16B slot 0..31
    const int lo = cc & 7;

    // ---- issue W loads (4 x float4) ----
    float4 wv[4];
#pragma unroll
    for (int j = 0; j < 4; j++) wv[j] = *(const float4*)(wsrc + j * 4);

    // ---- issue x batch A (rows 0..7, 8 x float4) ----
    float4 xa[8];
#pragma unroll
    for (int j = 0; j < 8; j++) xa[j] = *(const float4*)(xsrc + j * 256 + cc);

    // ---- W -> LDS (waits only on wv) ----
#pragma unroll
    for (int j = 0; j < 4; j++) {
      t[r][cg + j * 4 + 0] = (_Float16)wv[j].x;
      t[r][cg + j * 4 + 1] = (_Float16)wv[j].y;
      t[r][cg + j * 4 + 2] = (_Float16)wv[j].z;
      t[r][cg + j * 4 + 3] = (_Float16)wv[j].w;
    }
    __syncthreads();

    // ---- issue x batch B (rows 8..15) BEFORE draining batch A ----
    float4 xb[8];
#pragma unroll
    for (int j = 0; j < 8; j++) xb[j] = *(const float4*)(xsrc + (8 + j) * 256 + cc);

    // ---- cvt + store batch A (swizzle: slot' = slot ^ (row&7)) ----
#pragma unroll
    for (int j = 0; j < 8; j++) {
      half4 h;
      h[0] = (_Float16)xa[j].x; h[1] = (_Float16)xa[j].y;
      h[2] = (_Float16)xa[j].z; h[3] = (_Float16)xa[j].w;
      *(half4*)(xdst + j * 256 + (((slot ^ (j & 7)) << 3) | lo)) = h;
    }

    // ---- Wt store from LDS ----
    _Float16* dst = Wt + ((size_t)c << 16) + (size_t)(hb * 64 + r) * 256 + kb * 64 + cg;
    half8 o0, o1;
#pragma unroll
    for (int j = 0; j < 8; j++) o0[j] = t[cg + j][r];
#pragma unroll
    for (int j = 0; j < 8; j++) o1[j] = t[cg + 8 + j][r];
    *(half8*)(dst) = o0;
    *(half8*)(dst + 8) = o1;

    // ---- cvt + store batch B ((8+j)&7 == j&7) ----
#pragma unroll
    for (int j = 0; j < 8; j++) {
      half4 h;
      h[0] = (_Float16)xb[j].x; h[1] = (_Float16)xb[j].y;
      h[2] = (_Float16)xb[j].z; h[3] = (_Float16)xb[j].w;
      *(half4*)(xdst + (8 + j) * 256 + (((slot ^ (j & 7)) << 3) | lo)) = h;
    }
  } else {
    // ---- bucketing, latency-flat: all cat ids staged to LDS first ----
    __shared__ int scat[N_SAMPLES];   // 16 KB
    __shared__ int hist[N_CATS];
    __shared__ int poffs[N_CATS];
    __shared__ int curs[N_CATS];

    // issue the 16KB cat bulk-load FIRST (4 x int4 per thread)
    int4 cv[4];
#pragma unroll
    for (int j = 0; j < 4; j++)
      cv[j] = *(const int4*)(cat + (size_t)(j * 256 + tid) * 4);

    // init stores overlap the cat loads' latency
    if (tid < N_CATS) hist[tid] = 0;
    if (tid < N_CATS) curs[tid] = 0;
    for (int i = tid; i < MAX_PADDED; i += 256) ord[i] = -1;
    for (int i = tid; i < NGROUP; i += 256) gcat[i] = 0;

    // land cats in LDS
#pragma unroll
    for (int j = 0; j < 4; j++)
      *(int4*)(scat + (size_t)(j * 256 + tid) * 4) = cv[j];
    __syncthreads();

    // histogram out of LDS (no global latency)
    for (int i = tid; i < N_SAMPLES; i += 256) atomicAdd(&hist[scat[i]], 1);
    __syncthreads();
    if (tid == 0) {
      int run = 0;
      for (int c = 0; c < N_CATS; c++) {
        poffs[c] = run;
        run += ((hist[c] + SPB - 1) / SPB) * SPB;
      }
    }
    __syncthreads();
    if (tid < N_CATS) {
      const int c = tid;
      const int g0 = poffs[c] >> 2;
      const int ng = (hist[c] + SPB - 1) >> 2;
      for (int g = 0; g < ng; g++) gcat[g0 + g] = c;
    }
    // scatter out of LDS (ord stores fire-and-forget)
    for (int i = tid; i < N_SAMPLES; i += 256) {
      int c = scat[i];
      int p = poffs[c] + atomicAdd(&curs[c], 1);
      ord[p] = i;
    }
  }
}

// ---------------- main GEMM (R11 body, unchanged) ----------------
__global__ __launch_bounds__(256, 5)
void gemm_dma(const _Float16* __restrict__ x16, const float* __restrict__ bias,
              const _Float16* __restrict__ Wt, const int* __restrict__ ord,
              const int* __restrict__ gcat, float* __restrict__ out) {
  __shared__ __align__(16) _Float16 sA[64 * 256];  // 32 KB

  const int tid = threadIdx.x;
  const int B = blockIdx.x;
  const int xcd = B & 7;
  const int slot = B >> 3;
  const int h_half = slot & 1;
  const int group = xcd * GPX + (slot >> 1);
  const int h0 = h_half << 7;

  const int cat = gcat[group];
  const int4 sm = *(const int4*)(ord + group * 4);
  if (sm.x < 0) return;

  const int wid  = tid >> 6;
  const int lane = tid & 63;
  const int l15  = lane & 15;
  const int quad = lane >> 4;

  const _Float16* wb = Wt + ((size_t)cat << 16) +
                       (size_t)(h0 + wid * 32 + l15) * K_DIM + quad * 8;

  // ---- B fragments kt=0..3 into slots 0..3 + bias: issue FIRST ----
  half8 bf[5][2];
#pragma unroll
  for (int kt = 0; kt < 4; kt++) {
    bf[kt][0] = *(const half8*)(wb + kt * 32);
    bf[kt][1] = *(const half8*)(wb + 16 * K_DIM + kt * 32);
  }
  const float bv0 = bias[cat * H_DIM + h0 + wid * 32 + l15];
  const float bv1 = bias[cat * H_DIM + h0 + wid * 32 + 16 + l15];
  __builtin_amdgcn_sched_barrier(0);

  // ---- A staging: wave w DMAs its sample (8 x 1KB, linear dest) ----
  const int smp0 = (wid == 0) ? sm.x : (wid == 1) ? sm.y : (wid == 2) ? sm.z : sm.w;
  const int smp  = (smp0 >= 0) ? smp0 : sm.x;  // padded rows: junk, never stored
  const _Float16* asrc = x16 + ((size_t)smp << 12) + (lane << 3);
  _Float16* adst = sA + wid * 4096;
#pragma unroll
  for (int i = 0; i < 8; i++)
    GLOAD_LDS(asrc + i * 512, adst + i * 512);

  floatx4 acc[4][2];
#pragma unroll
  for (int i = 0; i < 4; i++)
#pragma unroll
    for (int j = 0; j < 2; j++)
#pragma unroll
      for (int e = 0; e < 4; e++) acc[i][j][e] = 0.0f;

  __syncthreads();  // the ONLY barrier (vmcnt(0) drain completes DMA + bf kt0-3)

  // ---- MFMA loop: 5-slot rotating B prefetch; swizzled conflict-free A reads ----
#pragma unroll
  for (int kt = 0; kt < 8; kt++) {
    if (kt < 4) {
      bf[(kt + 4) % 5][0] = *(const half8*)(wb + (kt + 4) * 32);
      bf[(kt + 4) % 5][1] = *(const half8*)(wb + 16 * K_DIM + (kt + 4) * 32);
      __builtin_amdgcn_sched_barrier(0);
    }
    half8 af[4];
#pragma unroll
    for (int mt = 0; mt < 4; mt++)
      af[mt] = *(const half8*)&sA[(size_t)(mt * 16 + l15) * 256 +
                                  (((kt * 4 + quad) ^ (l15 & 7)) << 3)];
#pragma unroll
    for (int mt = 0; mt < 4; mt++) {
      acc[mt][0] = __builtin_amdgcn_mfma_f32_16x16x32_f16(af[mt], bf[kt % 5][0], acc[mt][0], 0, 0, 0);
      acc[mt][1] = __builtin_amdgcn_mfma_f32_16x16x32_f16(af[mt], bf[kt % 5][1], acc[mt][1], 0, 0, 0);
    }
  }

  // ---- epilogue: C/D layout col=lane&15, row=quad*4+reg ----
  const int srow[4] = {sm.x, sm.y, sm.z, sm.w};
#pragma unroll
  for (int mt = 0; mt < 4; mt++) {
    const int s = srow[mt];
    if (s < 0) continue;
    float* obase = out + ((size_t)s << 12);
#pragma unroll
    for (int nt = 0; nt < 2; nt++) {
      const int col = h0 + wid * 32 + nt * 16 + l15;
      const float bv = nt ? bv1 : bv0;
#pragma unroll
      for (int rr = 0; rr < 4; rr++) {
        const int row = quad * 4 + rr;
        obase[(size_t)row * H_DIM + col] = acc[mt][nt][rr] + bv;
      }
    }
  }
}

// ---------------- small-tier GEMM (reg-staged A) ----------------
__global__ __launch_bounds__(256, 3)
void gemm_small(const float* __restrict__ x, const float* __restrict__ bias,
                const _Float16* __restrict__ Wt, const int* __restrict__ ord,
                const int* __restrict__ gcat, float* __restrict__ out) {
  __shared__ __align__(16) _Float16 sA[64 * AROW];

  const int tid = threadIdx.x;
  const int B = blockIdx.x;
  const int xcd = B & 7;
  const int slot = B >> 3;
  const int h_half = slot & 1;
  const int group = xcd * GPX + (slot >> 1);
  const int h0 = h_half << 7;

  const int cat = gcat[group];
  const int4 sm = *(const int4*)(ord + group * 4);
  if (sm.x < 0) return;

  const int wid  = tid >> 6;
  const int lane = tid & 63;
  const int l15  = lane & 15;
  const int quad = lane >> 4;

  const _Float16* wb = Wt + ((size_t)cat << 16) +
                       (size_t)(h0 + wid * 32 + l15) * K_DIM + quad * 8;

  half8 bf[5][2];
#pragma unroll
  for (int kt = 0; kt < 4; kt++) {
    bf[kt][0] = *(const half8*)(wb + kt * 32);
    bf[kt][1] = *(const half8*)(wb + 16 * K_DIM + kt * 32);
  }
  const float bv0 = bias[cat * H_DIM + h0 + wid * 32 + l15];
  const float bv1 = bias[cat * H_DIM + h0 + wid * 32 + 16 + l15];
  __builtin_amdgcn_sched_barrier(0);

  const int smp = (wid == 0) ? sm.x : (wid == 1) ? sm.y : (wid == 2) ? sm.z : sm.w;
  const float* asrc = (smp >= 0) ? (x + ((size_t)smp << 12)) : nullptr;
  _Float16* adst = sA + (size_t)(wid * 16) * AROW;
  if (asrc) {
#pragma unroll
    for (int j = 0; j < 16; j++) {
      float4 v = *(const float4*)(asrc + j * 256 + lane * 4);
      half4 h;
      h[0] = (_Float16)v.x; h[1] = (_Float16)v.y;
      h[2] = (_Float16)v.z; h[3] = (_Float16)v.w;
      *(half4*)(adst + (size_t)j * AROW + lane * 4) = h;
    }
  } else {
    half4 h;
#pragma unroll
    for (int e = 0; e < 4; e++) h[e] = (_Float16)0.0f;
#pragma unroll
    for (int j = 0; j < 16; j++)
      *(half4*)(adst + (size_t)j * AROW + lane * 4) = h;
  }

  floatx4 acc[4][2];
#pragma unroll
  for (int i = 0; i < 4; i++)
#pragma unroll
    for (int j = 0; j < 2; j++)
#pragma unroll
      for (int e = 0; e < 4; e++) acc[i][j][e] = 0.0f;

  __syncthreads();

#pragma unroll
  for (int kt = 0; kt < 8; kt++) {
    if (kt < 4) {
      bf[(kt + 4) % 5][0] = *(const half8*)(wb + (kt + 4) * 32);
      bf[(kt + 4) % 5][1] = *(const half8*)(wb + 16 * K_DIM + (kt + 4) * 32);
      __builtin_amdgcn_sched_barrier(0);
    }
    half8 af[4];
#pragma unroll
    for (int mt = 0; mt < 4; mt++)
      af[mt] = *(const half8*)&sA[(size_t)(mt * 16 + l15) * AROW + kt * 32 + quad * 8];
#pragma unroll
    for (int mt = 0; mt < 4; mt++) {
      acc[mt][0] = __builtin_amdgcn_mfma_f32_16x16x32_f16(af[mt], bf[kt % 5][0], acc[mt][0], 0, 0, 0);
      acc[mt][1] = __builtin_amdgcn_mfma_f32_16x16x32_f16(af[mt], bf[kt % 5][1], acc[mt][1], 0, 0, 0);
    }
  }

  const int srow[4] = {sm.x, sm.y, sm.z, sm.w};
#pragma unroll
  for (int mt = 0; mt < 4; mt++) {
    const int s = srow[mt];
    if (s < 0) continue;
    float* obase = out + ((size_t)s << 12);
#pragma unroll
    for (int nt = 0; nt < 2; nt++) {
      const int col = h0 + wid * 32 + nt * 16 + l15;
      const float bv = nt ? bv1 : bv0;
#pragma unroll
      for (int rr = 0; rr < 4; rr++) {
        const int row = quad * 4 + rr;
        obase[(size_t)row * H_DIM + col] = acc[mt][nt][rr] + bv;
      }
    }
  }
}

// ---------------- fallback (ws too small): naive fp32 ----------------
__global__ __launch_bounds__(256)
void naive_kernel(const float* __restrict__ x, const int* __restrict__ cat,
                  const float* __restrict__ W, const float* __restrict__ bias,
                  float* __restrict__ out) {
  __shared__ float sx[16 * 256];
  const int n = blockIdx.x;
  const int tid = threadIdx.x;
  const int c = cat[n];
  const float* xs = x + (size_t)n * 16 * 256;
  for (int i = tid; i < 16 * 256; i += 256) sx[i] = xs[i];
  __syncthreads();
  const float* Wc = W + ((size_t)c << 16);
  float accv[16];
  float bv = bias[c * 256 + tid];
#pragma unroll
  for (int m = 0; m < 16; m++) accv[m] = bv;
  for (int k = 0; k < 256; k++) {
    float w = Wc[(size_t)k * 256 + tid];
#pragma unroll
    for (int m = 0; m < 16; m++) accv[m] += sx[m * 256 + k] * w;
  }
#pragma unroll
  for (int m = 0; m < 16; m++) out[((size_t)n * 16 + m) * 256 + tid] = accv[m];
}

// ---------------- launcher ----------------
extern "C" void kernel_launch(void* const* d_in, const int* in_sizes, int n_in,
                              void* d_out, int out_size, void* d_ws, size_t ws_size,
                              hipStream_t stream) {
  const float* x    = (const float*)d_in[0];
  const int*   cat  = (const int*)d_in[1];
  const float* W    = (const float*)d_in[2];
  const float* bias = (const float*)d_in[3];
  float* out = (float*)d_out;

  char* ws = (char*)d_ws;
  if (ws_size >= WS_NEED_F) {
    _Float16* Wt  = (_Float16*)ws;
    _Float16* x16 = (_Float16*)(ws + WT_BYTES);
    int* gcat = (int*)(ws + GCAT_OFF_F);
    int* ord  = (int*)(ws + ORD_OFF_F);
    prep_combined<<<1025, 256, 0, stream>>>(W, Wt, cat, ord, gcat, x, x16);
    gemm_dma<<<GEMM_GRID, 256, 0, stream>>>(x16, bias, Wt, ord, gcat, out);
  } else if (ws_size >= WS_NEED_S) {
    _Float16* Wt = (_Float16*)ws;
    int* gcat = (int*)(ws + GCAT_OFF_S);
    int* ord  = (int*)(ws + ORD_OFF_S);
    prep_combined<<<1025, 256, 0, stream>>>(W, Wt, cat, ord, gcat, x, nullptr);
    gemm_small<<<GEMM_GRID, 256, 0, stream>>>(x, bias, Wt, ord, gcat, out);
  } else {
    naive_kernel<<<N_SAMPLES, 256, 0, stream>>>(x, cat, W, bias, out);
  }
}

// Round 15
// 153.175 us; speedup vs baseline: 1.0658x; 1.0079x over previous
//
#include <hip/hip_runtime.h>
#include <hip/hip_bf16.h>
#include <stdint.h>

#define N_SAMPLES 4096
#define M_ROWS 16
#define K_DIM 256
#define H_DIM 256
#define N_CATS 64
#define SPB 4                                        // samples per group (64 rows)
#define MAX_PADDED (N_SAMPLES + N_CATS * (SPB - 1))  // 4288
#define NGROUP (MAX_PADDED / SPB)                    // 1072
#define GPX (NGROUP / 8)                             // 134 groups per XCD
#define GEMM_GRID (NGROUP * 2)                       // 2144 units (group x h-half)
#define AROW 264                                     // small-tier fallback layout

typedef _Float16 half8 __attribute__((ext_vector_type(8)));
typedef _Float16 half4 __attribute__((ext_vector_type(4)));
typedef float floatx4 __attribute__((ext_vector_type(4)));

// async global->LDS DMA, 16B per lane (dest = uniform base + lane*16)
#define GLOAD_LDS(g, l)                                          \
  __builtin_amdgcn_global_load_lds(                              \
      (const __attribute__((address_space(1))) void*)(g),        \
      (__attribute__((address_space(3))) void*)(l), 16, 0, 0)

// ---- workspace layout ----
// full tier: Wt (8MB) | x16 (32MB, swizzled f16) | gcat | ord
#define WT_BYTES  ((size_t)N_CATS * K_DIM * H_DIM * 2)
#define X16_BYTES ((size_t)N_SAMPLES * M_ROWS * K_DIM * 2)
#define GCAT_OFF_F (WT_BYTES + X16_BYTES)
#define ORD_OFF_F  (GCAT_OFF_F + 4288)
#define WS_NEED_F  (ORD_OFF_F + (size_t)MAX_PADDED * 4)
// small tier (no x16): Wt | gcat | ord
#define GCAT_OFF_S WT_BYTES
#define ORD_OFF_S  (WT_BYTES + 4288)
#define WS_NEED_S  (ORD_OFF_S + (size_t)MAX_PADDED * 4)

// ---------------- prep: R7's fine-grained layout + R14's LDS bucketing ----------------
// R14 post-mortem: fixing the bucketing straggler (LDS-staged cat ids) was the
// win (-8us). But R14's balanced 1025-block copy was never the best-measured
// copy structure -- R7's 5121-block fine-grained split (1-sample x-blocks,
// 4 loads/thread, latency hidden by block-level parallelism) ran its copy
// in ~20-25us, masked then by the old 48us straggler.
// This round: R7 copy granularity (verbatim) + R14 bucketing (verbatim).
//   blocks 0..1023:   W-tile transpose (R7)
//   block  1024:      bucketing w/ LDS-staged cat ids (R14)
//   blocks 1025..5120: x -> x16 swizzled, one sample per block (R7)
__global__ __launch_bounds__(256)
void prep_combined(const float* __restrict__ W, _Float16* __restrict__ Wt,
                   const int* __restrict__ cat, int* __restrict__ ord,
                   int* __restrict__ gcat,
                   const float* __restrict__ x, _Float16* __restrict__ x16) {
  const int tid = threadIdx.x;
  const int bid = blockIdx.x;
  if (bid < 1024) {
    __shared__ _Float16 t[64][72];
    const int c  = bid >> 4;
    const int kb = (bid >> 2) & 3;
    const int hb = bid & 3;
    const int r  = tid >> 2;
    const int cg = (tid & 3) * 16;
    const float* src = W + ((size_t)c << 16) + (size_t)(kb * 64 + r) * 256 + hb * 64 + cg;
#pragma unroll
    for (int j = 0; j < 16; j += 4) {
      float4 v = *(const float4*)(src + j);
      t[r][cg + j + 0] = (_Float16)v.x;
      t[r][cg + j + 1] = (_Float16)v.y;
      t[r][cg + j + 2] = (_Float16)v.z;
      t[r][cg + j + 3] = (_Float16)v.w;
    }
    __syncthreads();
    _Float16* dst = Wt + ((size_t)c << 16) + (size_t)(hb * 64 + r) * 256 + kb * 64 + cg;
    half8 o0, o1;
#pragma unroll
    for (int j = 0; j < 8; j++) o0[j] = t[cg + j][r];
#pragma unroll
    for (int j = 0; j < 8; j++) o1[j] = t[cg + 8 + j][r];
    *(half8*)(dst) = o0;
    *(half8*)(dst + 8) = o1;
  } else if (bid == 1024) {
    // ---- bucketing, latency-flat: all cat ids staged to LDS first (R14) ----
    __shared__ int scat[N_SAMPLES];   // 16 KB
    __shared__ int hist[N_CATS];
    __shared__ int poffs[N_CATS];
    __shared__ int curs[N_CATS];

    // issue the 16KB cat bulk-load FIRST (4 x int4 per thread)
    int4 cv[4];
#pragma unroll
    for (int j = 0; j < 4; j++)
      cv[j] = *(const int4*)(cat + (size_t)(j * 256 + tid) * 4);

    // init stores overlap the cat loads' latency
    if (tid < N_CATS) hist[tid] = 0;
    if (tid < N_CATS) curs[tid] = 0;
    for (int i = tid; i < MAX_PADDED; i += 256) ord[i] = -1;
    for (int i = tid; i < NGROUP; i += 256) gcat[i] = 0;

    // land cats in LDS
#pragma unroll
    for (int j = 0; j < 4; j++)
      *(int4*)(scat + (size_t)(j * 256 + tid) * 4) = cv[j];
    __syncthreads();

    // histogram out of LDS (no global latency)
    for (int i = tid; i < N_SAMPLES; i += 256) atomicAdd(&hist[scat[i]], 1);
    __syncthreads();
    if (tid == 0) {
      int run = 0;
      for (int c = 0; c < N_CATS; c++) {
        poffs[c] = run;
        run += ((hist[c] + SPB - 1) / SPB) * SPB;
      }
    }
    __syncthreads();
    if (tid < N_CATS) {
      const int c = tid;
      const int g0 = poffs[c] >> 2;
      const int ng = (hist[c] + SPB - 1) >> 2;
      for (int g = 0; g < ng; g++) gcat[g0 + g] = c;
    }
    // scatter out of LDS (ord stores fire-and-forget)
    for (int i = tid; i < N_SAMPLES; i += 256) {
      int c = scat[i];
      int p = poffs[c] + atomicAdd(&curs[c], 1);
      ord[p] = i;
    }
  } else {
    // ---- x -> x16 (16B-slot XOR swizzle by row&7) : one sample per block (R7) ----
    const int s = bid - 1025;
    const float* src = x + ((size_t)s << 12);
    _Float16* dst = x16 + ((size_t)s << 12);
#pragma unroll
    for (int it = 0; it < 4; it++) {
      const int r = it * 4 + (tid >> 6);          // 0..15
      const int c = (tid & 63) << 2;              // 0..252 step 4
      float4 v = *(const float4*)(src + r * 256 + c);
      half4 h;
      h[0] = (_Float16)v.x; h[1] = (_Float16)v.y;
      h[2] = (_Float16)v.z; h[3] = (_Float16)v.w;
      const int slot = c >> 3;                    // 16B slot 0..31
      *(half4*)(dst + r * 256 + (((slot ^ (r & 7)) << 3) | (c & 7))) = h;
    }
  }
}

// ---------------- main GEMM (R14 body, unchanged) ----------------
__global__ __launch_bounds__(256, 5)
void gemm_dma(const _Float16* __restrict__ x16, const float* __restrict__ bias,
              const _Float16* __restrict__ Wt, const int* __restrict__ ord,
              const int* __restrict__ gcat, float* __restrict__ out) {
  __shared__ __align__(16) _Float16 sA[64 * 256];  // 32 KB

  const int tid = threadIdx.x;
  const int B = blockIdx.x;
  const int xcd = B & 7;
  const int slot = B >> 3;
  const int h_half = slot & 1;
  const int group = xcd * GPX + (slot >> 1);
  const int h0 = h_half << 7;

  const int cat = gcat[group];
  const int4 sm = *(const int4*)(ord + group * 4);
  if (sm.x < 0) return;

  const int wid  = tid >> 6;
  const int lane = tid & 63;
  const int l15  = lane & 15;
  const int quad = lane >> 4;

  const _Float16* wb = Wt + ((size_t)cat << 16) +
                       (size_t)(h0 + wid * 32 + l15) * K_DIM + quad * 8;

  // ---- B fragments kt=0..3 into slots 0..3 + bias: issue FIRST ----
  half8 bf[5][2];
#pragma unroll
  for (int kt = 0; kt < 4; kt++) {
    bf[kt][0] = *(const half8*)(wb + kt * 32);
    bf[kt][1] = *(const half8*)(wb + 16 * K_DIM + kt * 32);
  }
  const float bv0 = bias[cat * H_DIM + h0 + wid * 32 + l15];
  const float bv1 = bias[cat * H_DIM + h0 + wid * 32 + 16 + l15];
  __builtin_amdgcn_sched_barrier(0);

  // ---- A staging: wave w DMAs its sample (8 x 1KB, linear dest) ----
  const int smp0 = (wid == 0) ? sm.x : (wid == 1) ? sm.y : (wid == 2) ? sm.z : sm.w;
  const int smp  = (smp0 >= 0) ? smp0 : sm.x;  // padded rows: junk, never stored
  const _Float16* asrc = x16 + ((size_t)smp << 12) + (lane << 3);
  _Float16* adst = sA + wid * 4096;
#pragma unroll
  for (int i = 0; i < 8; i++)
    GLOAD_LDS(asrc + i * 512, adst + i * 512);

  floatx4 acc[4][2];
#pragma unroll
  for (int i = 0; i < 4; i++)
#pragma unroll
    for (int j = 0; j < 2; j++)
#pragma unroll
      for (int e = 0; e < 4; e++) acc[i][j][e] = 0.0f;

  __syncthreads();  // the ONLY barrier (vmcnt(0) drain completes DMA + bf kt0-3)

  // ---- MFMA loop: 5-slot rotating B prefetch; swizzled conflict-free A reads ----
#pragma unroll
  for (int kt = 0; kt < 8; kt++) {
    if (kt < 4) {
      bf[(kt + 4) % 5][0] = *(const half8*)(wb + (kt + 4) * 32);
      bf[(kt + 4) % 5][1] = *(const half8*)(wb + 16 * K_DIM + (kt + 4) * 32);
      __builtin_amdgcn_sched_barrier(0);
    }
    half8 af[4];
#pragma unroll
    for (int mt = 0; mt < 4; mt++)
      af[mt] = *(const half8*)&sA[(size_t)(mt * 16 + l15) * 256 +
                                  (((kt * 4 + quad) ^ (l15 & 7)) << 3)];
#pragma unroll
    for (int mt = 0; mt < 4; mt++) {
      acc[mt][0] = __builtin_amdgcn_mfma_f32_16x16x32_f16(af[mt], bf[kt % 5][0], acc[mt][0], 0, 0, 0);
      acc[mt][1] = __builtin_amdgcn_mfma_f32_16x16x32_f16(af[mt], bf[kt % 5][1], acc[mt][1], 0, 0, 0);
    }
  }

  // ---- epilogue: C/D layout col=lane&15, row=quad*4+reg ----
  const int srow[4] = {sm.x, sm.y, sm.z, sm.w};
#pragma unroll
  for (int mt = 0; mt < 4; mt++) {
    const int s = srow[mt];
    if (s < 0) continue;
    float* obase = out + ((size_t)s << 12);
#pragma unroll
    for (int nt = 0; nt < 2; nt++) {
      const int col = h0 + wid * 32 + nt * 16 + l15;
      const float bv = nt ? bv1 : bv0;
#pragma unroll
      for (int rr = 0; rr < 4; rr++) {
        const int row = quad * 4 + rr;
        obase[(size_t)row * H_DIM + col] = acc[mt][nt][rr] + bv;
      }
    }
  }
}

// ---------------- small-tier GEMM (reg-staged A) ----------------
__global__ __launch_bounds__(256, 3)
void gemm_small(const float* __restrict__ x, const float* __restrict__ bias,
                const _Float16* __restrict__ Wt, const int* __restrict__ ord,
                const int* __restrict__ gcat, float* __restrict__ out) {
  __shared__ __align__(16) _Float16 sA[64 * AROW];

  const int tid = threadIdx.x;
  const int B = blockIdx.x;
  const int xcd = B & 7;
  const int slot = B >> 3;
  const int h_half = slot & 1;
  const int group = xcd * GPX + (slot >> 1);
  const int h0 = h_half << 7;

  const int cat = gcat[group];
  const int4 sm = *(const int4*)(ord + group * 4);
  if (sm.x < 0) return;

  const int wid  = tid >> 6;
  const int lane = tid & 63;
  const int l15  = lane & 15;
  const int quad = lane >> 4;

  const _Float16* wb = Wt + ((size_t)cat << 16) +
                       (size_t)(h0 + wid * 32 + l15) * K_DIM + quad * 8;

  half8 bf[5][2];
#pragma unroll
  for (int kt = 0; kt < 4; kt++) {
    bf[kt][0] = *(const half8*)(wb + kt * 32);
    bf[kt][1] = *(const half8*)(wb + 16 * K_DIM + kt * 32);
  }
  const float bv0 = bias[cat * H_DIM + h0 + wid * 32 + l15];
  const float bv1 = bias[cat * H_DIM + h0 + wid * 32 + 16 + l15];
  __builtin_amdgcn_sched_barrier(0);

  const int smp = (wid == 0) ? sm.x : (wid == 1) ? sm.y : (wid == 2) ? sm.z : sm.w;
  const float* asrc = (smp >= 0) ? (x + ((size_t)smp << 12)) : nullptr;
  _Float16* adst = sA + (size_t)(wid * 16) * AROW;
  if (asrc) {
#pragma unroll
    for (int j = 0; j < 16; j++) {
      float4 v = *(const float4*)(asrc + j * 256 + lane * 4);
      half4 h;
      h[0] = (_Float16)v.x; h[1] = (_Float16)v.y;
      h[2] = (_Float16)v.z; h[3] = (_Float16)v.w;
      *(half4*)(adst + (size_t)j * AROW + lane * 4) = h;
    }
  } else {
    half4 h;
#pragma unroll
    for (int e = 0; e < 4; e++) h[e] = (_Float16)0.0f;
#pragma unroll
    for (int j = 0; j < 16; j++)
      *(half4*)(adst + (size_t)j * AROW + lane * 4) = h;
  }

  floatx4 acc[4][2];
#pragma unroll
  for (int i = 0; i < 4; i++)
#pragma unroll
    for (int j = 0; j < 2; j++)
#pragma unroll
      for (int e = 0; e < 4; e++) acc[i][j][e] = 0.0f;

  __syncthreads();

#pragma unroll
  for (int kt = 0; kt < 8; kt++) {
    if (kt < 4) {
      bf[(kt + 4) % 5][0] = *(const half8*)(wb + (kt + 4) * 32);
      bf[(kt + 4) % 5][1] = *(const half8*)(wb + 16 * K_DIM + (kt + 4) * 32);
      __builtin_amdgcn_sched_barrier(0);
    }
    half8 af[4];
#pragma unroll
    for (int mt = 0; mt < 4; mt++)
      af[mt] = *(const half8*)&sA[(size_t)(mt * 16 + l15) * AROW + kt * 32 + quad * 8];
#pragma unroll
    for (int mt = 0; mt < 4; mt++) {
      acc[mt][0] = __builtin_amdgcn_mfma_f32_16x16x32_f16(af[mt], bf[kt % 5][0], acc[mt][0], 0, 0, 0);
      acc[mt][1] = __builtin_amdgcn_mfma_f32_16x16x32_f16(af[mt], bf[kt % 5][1], acc[mt][1], 0, 0, 0);
    }
  }

  const int srow[4] = {sm.x, sm.y, sm.z, sm.w};
#pragma unroll
  for (int mt = 0; mt < 4; mt++) {
    const int s = srow[mt];
    if (s < 0) continue;
    float* obase = out + ((size_t)s << 12);
#pragma unroll
    for (int nt = 0; nt < 2; nt++) {
      const int col = h0 + wid * 32 + nt * 16 + l15;
      const float bv = nt ? bv1 : bv0;
#pragma unroll
      for (int rr = 0; rr < 4; rr++) {
        const int row = quad * 4 + rr;
        obase[(size_t)row * H_DIM + col] = acc[mt][nt][rr] + bv;
      }
    }
  }
}

// ---------------- fallback (ws too small): naive fp32 ----------------
__global__ __launch_bounds__(256)
void naive_kernel(const float* __restrict__ x, const int* __restrict__ cat,
                  const float* __restrict__ W, const float* __restrict__ bias,
                  float* __restrict__ out) {
  __shared__ float sx[16 * 256];
  const int n = blockIdx.x;
  const int tid = threadIdx.x;
  const int c = cat[n];
  const float* xs = x + (size_t)n * 16 * 256;
  for (int i = tid; i < 16 * 256; i += 256) sx[i] = xs[i];
  __syncthreads();
  const float* Wc = W + ((size_t)c << 16);
  float accv[16];
  float bv = bias[c * 256 + tid];
#pragma unroll
  for (int m = 0; m < 16; m++) accv[m] = bv;
  for (int k = 0; k < 256; k++) {
    float w = Wc[(size_t)k * 256 + tid];
#pragma unroll
    for (int m = 0; m < 16; m++) accv[m] += sx[m * 256 + k] * w;
  }
#pragma unroll
  for (int m = 0; m < 16; m++) out[((size_t)n * 16 + m) * 256 + tid] = accv[m];
}

// ---------------- launcher ----------------
extern "C" void kernel_launch(void* const* d_in, const int* in_sizes, int n_in,
                              void* d_out, int out_size, void* d_ws, size_t ws_size,
                              hipStream_t stream) {
  const float* x    = (const float*)d_in[0];
  const int*   cat  = (const int*)d_in[1];
  const float* W    = (const float*)d_in[2];
  const float* bias = (const float*)d_in[3];
  float* out = (float*)d_out;

  char* ws = (char*)d_ws;
  if (ws_size >= WS_NEED_F) {
    _Float16* Wt  = (_Float16*)ws;
    _Float16* x16 = (_Float16*)(ws + WT_BYTES);
    int* gcat = (int*)(ws + GCAT_OFF_F);
    int* ord  = (int*)(ws + ORD_OFF_F);
    prep_combined<<<1025 + N_SAMPLES, 256, 0, stream>>>(W, Wt, cat, ord, gcat, x, x16);
    gemm_dma<<<GEMM_GRID, 256, 0, stream>>>(x16, bias, Wt, ord, gcat, out);
  } else if (ws_size >= WS_NEED_S) {
    _Float16* Wt = (_Float16*)ws;
    int* gcat = (int*)(ws + GCAT_OFF_S);
    int* ord  = (int*)(ws + ORD_OFF_S);
    prep_combined<<<1025, 256, 0, stream>>>(W, Wt, cat, ord, gcat, x, nullptr);
    gemm_small<<<GEMM_GRID, 256, 0, stream>>>(x, bias, Wt, ord, gcat, out);
  } else {
    naive_kernel<<<N_SAMPLES, 256, 0, stream>>>(x, cat, W, bias, out);
  }
}